// Round 1
// baseline (395.244 us; speedup 1.0000x reference)
//
#include <hip/hip_runtime.h>
#include <math.h>

typedef float f2v __attribute__((ext_vector_type(2)));
typedef float f4v __attribute__((ext_vector_type(4)));

#define TF 256          // f-tile size
#define NTILE 16        // 4096 / TF
#define FT 36864        // F*T floats per batch (4096*9)

__global__ __launch_bounds__(256) void scorer_kernel(
    const float* __restrict__ x,     // [B, F, T] = [B, 4096, 9]
    const float* __restrict__ th1,   // [2]
    const float* __restrict__ W1,    // [4096, 32]
    const float* __restrict__ b1,    // [32]
    const float* __restrict__ gamma, // [32]
    const float* __restrict__ beta,  // [32]
    const float* __restrict__ th2,   // [2]
    const float* __restrict__ W2,    // [32]
    const float* __restrict__ b2p,   // [1]
    float* __restrict__ out)         // [B, 9]
{
    __shared__ __align__(16) float xl[2 * TF * 9];   // 18432 B
    const int tid = threadIdx.x;
    const int b0 = blockIdx.x * 2;
    const int hg = tid & 7;    // h-group: channels hg*4 .. hg*4+3
    const int fc = tid >> 3;   // f-chunk: 8 consecutive f per tile
    const float* xb = x + (size_t)b0 * FT;

    float acc[2][9][4];
    #pragma unroll
    for (int b = 0; b < 2; ++b)
        #pragma unroll
        for (int t = 0; t < 9; ++t)
            #pragma unroll
            for (int j = 0; j < 4; ++j) acc[b][t][j] = 0.f;

    const f4v* __restrict__ W1v = (const f4v*)W1;   // index f*8 + hg

    for (int tile = 0; tile < NTILE; ++tile) {
        const int fbase = tile * TF;
        __syncthreads();   // previous compute done reading xl
        // ---- stage both batches' x tile into LDS (nontemporal float2) ----
        const f2v* s0 = (const f2v*)(xb + fbase * 9);
        const f2v* s1 = (const f2v*)(xb + FT + fbase * 9);
        f2v* dst = (f2v*)xl;
        #pragma unroll
        for (int k = 0; k < 9; ++k) {
            int s = tid + k * 256;                       // 0..2303
            f2v v;
            if (s < 1152) v = __builtin_nontemporal_load(&s0[s]);
            else          v = __builtin_nontemporal_load(&s1[s - 1152]);
            dst[s] = v;
        }
        __syncthreads();
        if (tile == 0) {
            // fold plane_rotate(theta1) into the 4 affected f-rows of X
            if (tid < 36) {
                int bb = tid / 18, r = tid % 18, t = r >> 1, p = r & 1;
                float c = cosf(th1[p]), sn = sinf(th1[p]);
                float a  = xl[bb * 2304 + (2 * p) * 9 + t];
                float bv = xl[bb * 2304 + (2 * p + 1) * 9 + t];
                xl[bb * 2304 + (2 * p) * 9 + t]     = c * a - sn * bv;
                xl[bb * 2304 + (2 * p + 1) * 9 + t] = sn * a + c * bv;
            }
            __syncthreads();
        }
        // ---- compute: 8 f's x 9 t x 4 h x 2 batches ----
        const int f0 = fbase + fc * 8;
        #pragma unroll
        for (int i = 0; i < 8; ++i) {
            const f4v w = W1v[(size_t)(f0 + i) * 8 + hg];
            const float* xp = &xl[(fc * 8 + i) * 9];
            #pragma unroll
            for (int t = 0; t < 9; ++t) {
                float xv0 = xp[t];
                float xv1 = xp[t + 2304];
                acc[0][t][0] += xv0 * w.x;
                acc[0][t][1] += xv0 * w.y;
                acc[0][t][2] += xv0 * w.z;
                acc[0][t][3] += xv0 * w.w;
                acc[1][t][0] += xv1 * w.x;
                acc[1][t][1] += xv1 * w.y;
                acc[1][t][2] += xv1 * w.z;
                acc[1][t][3] += xv1 * w.w;
            }
        }
    }

    __syncthreads();   // all compute done; reuse xl for reduction

    // ---- butterfly reduce over the 8 f-chunks inside each wave ----
    float* af = (float*)acc;
    #pragma unroll
    for (int q = 0; q < 72; ++q) {
        float v = af[q];
        v += __shfl_xor(v, 8);
        v += __shfl_xor(v, 16);
        v += __shfl_xor(v, 32);
        af[q] = v;
    }
    const int wv = tid >> 6;
    const int lane = tid & 63;
    if (lane < 8) {                      // lane == hg for these lanes
        float* dstp = &xl[(wv * 8 + lane) * 72];
        #pragma unroll
        for (int q = 0; q < 72; ++q) dstp[q] = af[q];
    }
    __syncthreads();

    // ---- cross-wave sum + bias + modular phase norm -> g in LDS ----
    for (int o = tid; o < 576; o += 256) {
        int h = o & 31;
        int t = (o >> 5) % 9;
        int bb = o / 288;
        int hg2 = h >> 2, j = h & 3;
        int idx = bb * 36 + t * 4 + j;
        float v = xl[(0 * 8 + hg2) * 72 + idx]
                + xl[(1 * 8 + hg2) * 72 + idx]
                + xl[(2 * 8 + hg2) * 72 + idx]
                + xl[(3 * 8 + hg2) * 72 + idx];
        v += b1[h];
        float wr = v - 7.0f * floorf(v / 7.0f + 0.5f);
        float g = gamma[h] * wr + beta[h];
        xl[2304 + bb * 288 + t * 32 + h] = g;
    }
    __syncthreads();

    // ---- rotate(theta2), dot with W2, bias -> scores ----
    if (tid < 18) {
        int bb = tid / 9, t = tid % 9;
        const float* g = &xl[2304 + bb * 288 + t * 32];
        float c0 = cosf(th2[0]), s0r = sinf(th2[0]);
        float c1 = cosf(th2[1]), s1r = sinf(th2[1]);
        float sc = (c0 * g[0] - s0r * g[1]) * W2[0]
                 + (s0r * g[0] + c0 * g[1]) * W2[1]
                 + (c1 * g[2] - s1r * g[3]) * W2[2]
                 + (s1r * g[2] + c1 * g[3]) * W2[3];
        #pragma unroll
        for (int h = 4; h < 32; ++h) sc += g[h] * W2[h];
        sc += b2p[0];
        xl[2880 + bb * 9 + t] = sc;
    }
    __syncthreads();

    // ---- softmax over t=0..8, write output ----
    if (tid < 18) {
        int bb = tid / 9, t = tid % 9;
        const float* sb = &xl[2880 + bb * 9];
        float m = sb[0];
        #pragma unroll
        for (int k = 1; k < 9; ++k) m = fmaxf(m, sb[k]);
        float den = 0.f;
        #pragma unroll
        for (int k = 0; k < 9; ++k) den += expf(sb[k] - m);
        out[(size_t)(b0 + bb) * 9 + t] = expf(sb[t] - m) / den;
    }
}

extern "C" void kernel_launch(void* const* d_in, const int* in_sizes, int n_in,
                              void* d_out, int out_size, void* d_ws, size_t ws_size,
                              hipStream_t stream) {
    const float* x     = (const float*)d_in[0];
    const float* th1   = (const float*)d_in[1];
    const float* W1    = (const float*)d_in[2];
    const float* b1    = (const float*)d_in[3];
    const float* gamma = (const float*)d_in[4];
    const float* beta  = (const float*)d_in[5];
    const float* th2   = (const float*)d_in[6];
    const float* W2    = (const float*)d_in[7];
    const float* b2    = (const float*)d_in[8];
    float* out = (float*)d_out;

    const int B = in_sizes[0] / FT;   // 8192
    dim3 grid(B / 2), block(256);
    hipLaunchKernelGGL(scorer_kernel, grid, block, 0, stream,
                       x, th1, W1, b1, gamma, beta, th2, W2, b2, out);
}